// Round 3
// baseline (10928.887 us; speedup 1.0000x reference)
//
#include <hip/hip_runtime.h>
#include <stdint.h>

// ---------------------------------------------------------------------------
// 4-layer stacked LSTM -> fanout/LeakyReLU/fanin -> LSTM -> head(sigmoid)
// persistent producer/consumer pipeline.
//
// R4 (vs R2, the 7766us baseline; R3's XCD/L2 experiment hung and is dropped):
//  * REC step loop has ZERO barriers, ZERO LDS, ZERO fetch_add. Each of the
//    4 waves of a REC block is fully decoupled: it computes its 16 units,
//    stores them to the h ring (agent scope, LLC), publishes a per-group
//    step flag (16 flags per layer, own 64B lines), polls the 15 foreign
//    group flags with lanes 0-15 in parallel (wave reconvergence joins),
//    and loads its next-step MFMA A-fragments directly from the h ring.
//  * xg ring loads double-buffered one step ahead (latency hidden).
//  * Downstream consumers wait on the 16 step flags (lane-parallel).
//  * All cross-block traffic stays RELAXED AGENT scope (LLC) - the regime
//    R2 proved correct. No sc0/XCD tricks, no XCC_ID.
// ---------------------------------------------------------------------------

#define B_ 16
#define T_ 2048
#define H_ 256
#define NG 1024
#define F_ 1024
#define CHUNK 8
#define NCH 256            // T_/CHUNK
#define WH 128             // h ring depth (steps)
#define WXG 128            // xg ring depth (steps)
#define WCH 16             // chunk-granular ring depth
#define PREC 4
#define NRECB 20
#define NBLK 56
#define APITCH 264         // LDS row pitch (bf16 elems)
#define WELEM 262144       // 1024*256

typedef __attribute__((ext_vector_type(4))) float f32x4;
typedef __attribute__((ext_vector_type(8))) short bf16x8;
typedef unsigned long long ull;

// ---- workspace layout ----
#define OFF_XG   0ul
#define SZ_XG    (5ul*WXG*NG*B_*4ul)                 // f32 [5][128][1024][16]
#define OFF_H    (OFF_XG + SZ_XG)
#define SZ_H     (5ul*WH*B_*H_*2ul)                  // bf16 [5][128][16][256]
#define OFF_FO   (OFF_H + SZ_H)
#define SZ_FO    ((unsigned long)WCH*128ul*F_*2ul)   // bf16 [16][128][1024]
#define OFF_FI   (OFF_FO + SZ_FO)
#define SZ_FI    ((unsigned long)WCH*128ul*H_*2ul)   // bf16 [16][128][256]
#define OFF_WBF  (OFF_FI + SZ_FI)
#define SZ_WBF   (7ul*WELEM*2ul)
#define OFF_H4   (OFF_WBF + SZ_WBF)
#define OFF_FLAG (OFF_H4 + 16384ul + 256ul)
#define OFF_SF   (OFF_FLAG + 1024ul)                 // u32 [5][16][16] step flags
#define SZ_SF    (5ul*16ul*16ul*4ul)                 // 5120 B

// flag word indices (64B-line padded where contended)
#define FL_XGF(s)  (80 + (s)*16)     // [16] slots per stage, value tc+1
#define FL_FOF     160               // [16]
#define FL_FIF     176               // [16]
#define FL_XGP(s)  (192 + (s)*4)     // [5][4] producer progress (chunks)
#define FL_FOP     212               // [8]
#define FL_FIP     220               // [8]
#define FL_N       256

__device__ __forceinline__ unsigned short f2bf(float f) {
  unsigned int u = __float_as_uint(f);
  u = u + 0x7fffu + ((u >> 16) & 1u);
  return (unsigned short)(u >> 16);
}
__device__ __forceinline__ float sigm_f(float x) { return 1.0f / (1.0f + __expf(-x)); }
__device__ __forceinline__ float tanh_f(float x) {
  float e = __expf(-2.0f * fabsf(x));
  float r = (1.0f - e) / (1.0f + e);
  return x >= 0.0f ? r : -r;
}
__device__ __forceinline__ unsigned ld32(const void* p) {
  return __hip_atomic_load((const unsigned*)p, __ATOMIC_RELAXED, __HIP_MEMORY_SCOPE_AGENT);
}
__device__ __forceinline__ void st32(void* p, unsigned v) {
  __hip_atomic_store((unsigned*)p, v, __ATOMIC_RELAXED, __HIP_MEMORY_SCOPE_AGENT);
}
__device__ __forceinline__ ull ld64(const void* p) {
  return __hip_atomic_load((const ull*)p, __ATOMIC_RELAXED, __HIP_MEMORY_SCOPE_AGENT);
}
__device__ __forceinline__ void st64(void* p, ull v) {
  __hip_atomic_store((ull*)p, v, __ATOMIC_RELAXED, __HIP_MEMORY_SCOPE_AGENT);
}
// relaxed LLC spin (bounded: a protocol bug -> wrong output, not a hang)
__device__ __forceinline__ void spin_ge(unsigned int* p, unsigned int tgt) {
  int n = 0;
  while (ld32(p) < tgt) {
    __builtin_amdgcn_s_sleep(1);
    if (++n > 20000000) break;
  }
}

// ---------------------------------------------------------------------------
__global__ void k_prep(const float* __restrict__ w0ih, const float* __restrict__ w1ih,
                       const float* __restrict__ foW, const float* __restrict__ fiW,
                       unsigned char* ws) {
  unsigned short* wbf = (unsigned short*)(ws + OFF_WBF);
  unsigned int* flags = (unsigned int*)(ws + OFF_FLAG);
  if (blockIdx.x == 0 && threadIdx.x < FL_N) flags[threadIdx.x] = 0u;
  if (blockIdx.x == 1) {
    unsigned int* sf = (unsigned int*)(ws + OFF_SF);
    for (int i = threadIdx.x; i < 5 * 256; i += 256) sf[i] = 0u;
  }
  if (blockIdx.x >= 2 && blockIdx.x < 7) {   // zero h(-1): ring slot 127, each layer
    int l = blockIdx.x - 2;
    unsigned short* h_ring = (unsigned short*)(ws + OFF_H);
    ull* z = (ull*)(h_ring + ((size_t)l * WH + 127) * (B_ * H_));
    for (int i = threadIdx.x; i < (B_ * H_) / 4; i += 256) z[i] = 0ull;
  }
  int gid = blockIdx.x * 256 + threadIdx.x;
  if (gid < 7 * WELEM) {
    int which = gid >> 18;
    int idx = gid & (WELEM - 1);
    float v;
    if (which < 4)       v = w0ih[(size_t)which * WELEM + idx];
    else if (which == 4) v = w1ih[idx];
    else if (which == 5) v = foW[idx];
    else                 v = fiW[idx];
    wbf[gid] = f2bf(v);
  }
}

// ---------------------------------------------------------------------------
// issue the 8 xg ring loads (agent/LLC) for step TT into register buffer DST
#define ISSUE_XA(TT, DST) do { \
    const ull* xg8_ = (const ull*)(xg_ring + ((size_t)l * WXG + (size_t)((TT) & 127)) * (NG * B_)); \
    _Pragma("unroll") \
    for (int g_ = 0; g_ < 4; ++g_) { \
      size_t n8_ = (size_t)(g_ * 256 + unit) * 8 + quad * 2; \
      DST[g_][0] = ld64(xg8_ + n8_); \
      DST[g_][1] = ld64(xg8_ + n8_ + 1); \
    } \
  } while (0)

// One recurrent step, fully per-wave (no barriers, no LDS).
// XC = xg regs for this step (already in flight), XN = buffer to prefetch t+1.
#define REC_STEP(T, XC, XN) do { \
    const int t_ = (T); \
    if ((t_ & 7) == 0) { \
      int tc_ = t_ >> 3; \
      unsigned int* wp_ = (unsigned int*)0; unsigned wt_ = 0u; \
      if (lane == 0) { wp_ = xgf + (tc_ & 15); wt_ = (unsigned)(tc_ + 1); } \
      else if (l < 4 && tc_ >= WCH) { \
        if (l < 3) { if (lane <= 4) { wp_ = flags + FL_XGP(l + 1) + (lane - 1); wt_ = (unsigned)(tc_ - WCH + 1); } } \
        else       { if (lane <= 8) { wp_ = flags + FL_FOP + (lane - 1); wt_ = (unsigned)(tc_ - WCH + 1); } } \
      } \
      if (wp_) spin_ge(wp_, wt_); \
      ISSUE_XA(t_, XC); \
    } \
    /* wait for h(t-1): all 16 unit-group flags >= t (own trivially done) */ \
    if (lane < 16 && lane != u16) spin_ge(sfl + lane * 16, (unsigned)t_); \
    /* load MFMA A-frags (h(t-1), all 16 batches) straight from the ring */ \
    union AF_ { ull u[2]; bf16x8 v; } afu_[8]; \
    { const ull* hr8_ = (const ull*)(h_ring + ((size_t)l * WH + (size_t)((t_ - 1) & 127)) * (B_ * H_)); \
      _Pragma("unroll") \
      for (int kk_ = 0; kk_ < 8; ++kk_) { \
        size_t i8_ = (size_t)(c16 * 256 + kk_ * 32 + quad * 8) >> 2; \
        afu_[kk_].u[0] = ld64(hr8_ + i8_); \
        afu_[kk_].u[1] = ld64(hr8_ + i8_ + 1); } } \
    /* gates = h . Whh^T */ \
    f32x4 ac_[4]; \
    _Pragma("unroll") for (int g_ = 0; g_ < 4; ++g_) ac_[g_] = (f32x4){0.f, 0.f, 0.f, 0.f}; \
    _Pragma("unroll") \
    for (int kk_ = 0; kk_ < 8; ++kk_) { \
      _Pragma("unroll") \
      for (int g_ = 0; g_ < 4; ++g_) \
        ac_[g_] = __builtin_amdgcn_mfma_f32_16x16x32_bf16(afu_[kk_].v, bfr[g_][kk_], ac_[g_], 0, 0, 0); \
    } \
    if ((t_ & 7) != 7) ISSUE_XA(t_ + 1, XN);   /* prefetch next step's xg */ \
    /* elementwise cell; lane owns (b=quad*4+r, unit) */ \
    float hv_[4]; \
    _Pragma("unroll") \
    for (int r_ = 0; r_ < 4; ++r_) { \
      union { ull u; float f[2]; } u0_, u1_, u2_, u3_; \
      u0_.u = XC[0][r_ >> 1]; u1_.u = XC[1][r_ >> 1]; \
      u2_.u = XC[2][r_ >> 1]; u3_.u = XC[3][r_ >> 1]; \
      float iv_ = sigm_f(ac_[0][r_] + u0_.f[r_ & 1]); \
      float fv_ = sigm_f(ac_[1][r_] + u1_.f[r_ & 1]); \
      float gv_ = tanh_f(ac_[2][r_] + u2_.f[r_ & 1]); \
      float ov_ = sigm_f(ac_[3][r_] + u3_.f[r_ & 1]); \
      cst[r_] = fv_ * cst[r_] + iv_ * gv_; \
      hv_[r_] = ov_ * tanh_f(cst[r_]); \
      if (l == 4 && t_ == T_ - 1) h4_last[(quad * 4 + r_) * H_ + unit] = hv_[r_]; \
    } \
    /* pack bf16 pairs via shfl; even lanes store own units to the h ring */ \
    { unsigned short* hrw_ = h_ring + ((size_t)l * WH + (size_t)(t_ & 127)) * (B_ * H_); \
      _Pragma("unroll") \
      for (int r_ = 0; r_ < 4; ++r_) { \
        float oth_ = __shfl_xor(hv_[r_], 1, 64); \
        if ((lane & 1) == 0) { \
          unsigned pk2_ = (unsigned)f2bf(hv_[r_]) | ((unsigned)f2bf(oth_) << 16); \
          st32(hrw_ + (size_t)(quad * 4 + r_) * H_ + unit, pk2_); \
        } } } \
    asm volatile("s_waitcnt vmcnt(0)" ::: "memory");   /* ring stores at LLC */ \
    if (lane == 0) st32(sfl + u16 * 16, (unsigned)(t_ + 1)); \
  } while (0)

// ---------------------------------------------------------------------------
__global__ __launch_bounds__(256, 1) void k_pipe(
    const float* __restrict__ x,
    const float* __restrict__ w0hh, const float* __restrict__ b0,
    const float* __restrict__ fo_b, const float* __restrict__ fi_b,
    const float* __restrict__ w1hh, const float* __restrict__ b1,
    unsigned char* ws)
{
  __shared__ unsigned short smem[64 * APITCH];   // 33792 B (stream roles only)

  float*          xg_ring = (float*)(ws + OFF_XG);
  unsigned short* h_ring  = (unsigned short*)(ws + OFF_H);
  unsigned short* fo_ring = (unsigned short*)(ws + OFF_FO);
  unsigned short* fi_ring = (unsigned short*)(ws + OFF_FI);
  unsigned short* wbf     = (unsigned short*)(ws + OFF_WBF);
  float*          h4_last = (float*)(ws + OFF_H4);
  unsigned int*   flags   = (unsigned int*)(ws + OFF_FLAG);
  unsigned int*   sf      = (unsigned int*)(ws + OFF_SF);
#define SFL(L) (sf + (L) * 256)

  const int tid = threadIdx.x;
  const int lane = tid & 63;
  const int wave = tid >> 6;
  const int quad = lane >> 4;
  const int c16 = lane & 15;
  const int bid = blockIdx.x;

  if (bid < NRECB) {
    // ================= recurrent role: layer l, part p =================
    const int l = bid / PREC, p = bid % PREC;
    const int u16 = p * 4 + wave;          // unit-group 0..15 (16 units each)
    const int unit = u16 * 16 + c16;       // global unit 0..255
    const float* Whh = (l < 4) ? (w0hh + (size_t)l * NG * H_) : w1hh;

    bf16x8 bfr[4][8];   // B-frags: Whh[n][k], n = gate*256+unit
#pragma unroll
    for (int g = 0; g < 4; ++g) {
      const float* rp = Whh + (size_t)(g * 256 + unit) * H_ + quad * 8;
#pragma unroll
      for (int kk = 0; kk < 8; ++kk) {
        const float* q = rp + kk * 32;
        bf16x8 pk;
#pragma unroll
        for (int jj = 0; jj < 8; ++jj) pk[jj] = (short)f2bf(q[jj]);
        bfr[g][kk] = pk;
      }
    }
    float cst[4] = {0.f, 0.f, 0.f, 0.f};

    unsigned int* xgf = flags + FL_XGF(l);
    unsigned int* sfl = SFL(l);

    ull xaA[4][2], xaB[4][2];
    for (int t2 = 0; t2 < T_; t2 += 2) {
      REC_STEP(t2,     xaA, xaB);
      REC_STEP(t2 + 1, xaB, xaA);
    }
  } else {
    // ================= stream roles =================
    int sb = bid - NRECB, s, j, GSS;
    if (sb < 20)      { s = sb >> 2; j = sb & 3;  GSS = 4; }
    else if (sb < 28) { s = 5;       j = sb - 20; GSS = 8; }
    else              { s = 6;       j = sb - 28; GSS = 8; }
    const bool isXG = (s < 5), isFO = (s == 5), isFI = (s == 6);
    const unsigned short* Bw = wbf + (size_t)(isXG ? s : (isFO ? 5 : 6)) * WELEM;
    const float* bias = isXG ? ((s < 4) ? (b0 + s * NG) : b1) : (isFO ? fo_b : fi_b);
    unsigned int* myprog =
        flags + (isXG ? (FL_XGP(s) + j) : (isFO ? (FL_FOP + j) : (FL_FIP + j)));

    for (int tc = j; tc < NCH; tc += GSS) {
      // output-ring overwrite guard (lane-parallel, then barrier)
      if (tc >= WCH) {
        unsigned int tgt = (unsigned)(tc - WCH + 1);
        if (isXG)      { if (tid < 16) spin_ge(SFL(s) + tid * 16, 8u * tgt); }
        else if (isFO) { if (tid < 8)  spin_ge(flags + FL_FIP + tid, tgt); }
        else           { if (tid < 4)  spin_ge(flags + FL_XGP(4) + tid, tgt); }
      }
      // input readiness
      if (isXG) {
        if (s >= 1 && s <= 3) { if (tid < 16) spin_ge(SFL(s - 1) + tid * 16, 8u * (unsigned)(tc + 1)); }
        else if (s == 4)      { if (tid == 0) spin_ge(flags + FL_FIF + (tc & 15), (unsigned)(tc + 1)); }
      } else if (isFO) {
        if (tid < 16) spin_ge(SFL(3) + tid * 16, 8u * (unsigned)(tc + 1));
      } else {
        if (tid == 0) spin_ge(flags + FL_FOF + (tc & 15), (unsigned)(tc + 1));
      }
      __syncthreads();

      if (!isFI) {
        // [128,256] x [256,1024]
#pragma unroll
        for (int m_blk = 0; m_blk < 2; ++m_blk) {
          __syncthreads();
          { // stage 64 A rows into LDS (bf16)
            int rloc = tid >> 2;
            int k0 = (tid & 3) * 64;
            int row = m_blk * 64 + rloc;
            int tl = row >> 4, b = row & 15;
            int t = tc * CHUNK + tl;
            unsigned short* dst = &smem[rloc * APITCH + k0];
            if (s == 0) {
              const float* src = x + ((size_t)b * T_ + t) * H_ + k0;
#pragma unroll
              for (int i = 0; i < 16; ++i) {
                f32x4 v = *(const f32x4*)(src + i * 4);
                *(unsigned*)(dst + i * 4)     = (unsigned)f2bf(v[0]) | ((unsigned)f2bf(v[1]) << 16);
                *(unsigned*)(dst + i * 4 + 2) = (unsigned)f2bf(v[2]) | ((unsigned)f2bf(v[3]) << 16);
              }
            } else {
              const unsigned short* src;
              if (isXG && s <= 3)
                src = h_ring + ((size_t)(s - 1) * WH + (size_t)(t & 127)) * (B_ * H_) + b * H_ + k0;
              else if (isXG)  // s==4: fan-in output
                src = fi_ring + ((size_t)(tc & 15) * 128 + row) * H_ + k0;
              else            // FO: h3
                src = h_ring + ((size_t)3 * WH + (size_t)(t & 127)) * (B_ * H_) + b * H_ + k0;
#pragma unroll
              for (int i = 0; i < 16; ++i)
                *(ull*)(dst + i * 4) = ld64((const ull*)src + i);
            }
          }
          __syncthreads();
          bf16x8 afr[4][8];
#pragma unroll
          for (int mt = 0; mt < 4; ++mt)
#pragma unroll
            for (int kk = 0; kk < 8; ++kk)
              afr[mt][kk] = *(const bf16x8*)(&smem[(mt * 16 + c16) * APITCH + kk * 32 + quad * 8]);
          for (int nn = 0; nn < 16; ++nn) {
            int n = (wave * 16 + nn) * 16 + c16;
            const unsigned short* bp = Bw + (size_t)n * 256 + quad * 8;
            bf16x8 bfr2[8];
#pragma unroll
            for (int kk = 0; kk < 8; ++kk) bfr2[kk] = *(const bf16x8*)(bp + kk * 32);
            f32x4 ac[4];
#pragma unroll
            for (int mt = 0; mt < 4; ++mt) ac[mt] = (f32x4){0.f, 0.f, 0.f, 0.f};
#pragma unroll
            for (int kk = 0; kk < 8; ++kk)
#pragma unroll
              for (int mt = 0; mt < 4; ++mt)
                ac[mt] = __builtin_amdgcn_mfma_f32_16x16x32_bf16(afr[mt][kk], bfr2[kk], ac[mt], 0, 0, 0);
            float bn = bias[n];
            if (isXG) {
              ull* xg8 = (ull*)(xg_ring + (size_t)s * WXG * (NG * B_));
#pragma unroll
              for (int mt = 0; mt < 4; ++mt) {
                int t = tc * CHUNK + m_blk * 4 + mt;
                size_t bi = ((size_t)(t & 127) * (NG * B_) + (size_t)n * B_ + quad * 4) >> 1;
                union { ull u; float f[2]; } u0, u1;
                u0.f[0] = ac[mt][0] + bn; u0.f[1] = ac[mt][1] + bn;
                u1.f[0] = ac[mt][2] + bn; u1.f[1] = ac[mt][3] + bn;
                st64(xg8 + bi, u0.u);
                st64(xg8 + bi + 1, u1.u);
              }
            } else {  // FO: bias + LeakyReLU -> bf16 ring
#pragma unroll
              for (int mt = 0; mt < 4; ++mt) {
                int row = m_blk * 64 + mt * 16 + quad * 4;
#pragma unroll
                for (int r = 0; r < 4; ++r) {
                  float v = ac[mt][r] + bn;
                  v = v >= 0.f ? v : 0.2f * v;
                  float oth = __shfl_xor(v, 1, 64);
                  if ((lane & 1) == 0) {
                    unsigned pk = (unsigned)f2bf(v) | ((unsigned)f2bf(oth) << 16);
                    st32(fo_ring + ((size_t)(tc & 15) * 128 + row + r) * F_ + n, pk);
                  }
                }
              }
            }
          }
        }
      } else {
        // FI: [128,1024] x [1024,256]
        f32x4 acc[2][4][4];
#pragma unroll
        for (int a1 = 0; a1 < 2; ++a1)
#pragma unroll
          for (int a2 = 0; a2 < 4; ++a2)
#pragma unroll
            for (int a3 = 0; a3 < 4; ++a3) acc[a1][a2][a3] = (f32x4){0.f, 0.f, 0.f, 0.f};
#pragma unroll
        for (int ks = 0; ks < 4; ++ks) {
#pragma unroll
          for (int m_blk = 0; m_blk < 2; ++m_blk) {
            __syncthreads();
            {
              int rloc = tid >> 2;
              int k0 = (tid & 3) * 64;
              int row = m_blk * 64 + rloc;
              const unsigned short* src =
                  fo_ring + ((size_t)(tc & 15) * 128 + row) * F_ + ks * 256 + k0;
              unsigned short* dst = &smem[rloc * APITCH + k0];
#pragma unroll
              for (int i = 0; i < 16; ++i)
                *(ull*)(dst + i * 4) = ld64((const ull*)src + i);
            }
            __syncthreads();
            bf16x8 afr[4][8];
#pragma unroll
            for (int mt = 0; mt < 4; ++mt)
#pragma unroll
              for (int kk = 0; kk < 8; ++kk)
                afr[mt][kk] = *(const bf16x8*)(&smem[(mt * 16 + c16) * APITCH + kk * 32 + quad * 8]);
#pragma unroll
            for (int nn = 0; nn < 4; ++nn) {
              int n = (wave * 4 + nn) * 16 + c16;
              const unsigned short* bp = Bw + (size_t)n * 1024 + ks * 256 + quad * 8;
              bf16x8 bfr2[8];
#pragma unroll
              for (int kk = 0; kk < 8; ++kk) bfr2[kk] = *(const bf16x8*)(bp + kk * 32);
#pragma unroll
              for (int kk = 0; kk < 8; ++kk)
#pragma unroll
                for (int mt = 0; mt < 4; ++mt)
                  acc[m_blk][nn][mt] =
                      __builtin_amdgcn_mfma_f32_16x16x32_bf16(afr[mt][kk], bfr2[kk], acc[m_blk][nn][mt], 0, 0, 0);
            }
          }
        }
#pragma unroll
        for (int m_blk = 0; m_blk < 2; ++m_blk)
#pragma unroll
          for (int nn = 0; nn < 4; ++nn) {
            int n = (wave * 4 + nn) * 16 + c16;
            float bn = bias[n];
#pragma unroll
            for (int mt = 0; mt < 4; ++mt) {
              int row = m_blk * 64 + mt * 16 + quad * 4;
#pragma unroll
              for (int r = 0; r < 4; ++r) {
                float v = acc[m_blk][nn][mt][r] + bn;
                float oth = __shfl_xor(v, 1, 64);
                if ((lane & 1) == 0) {
                  unsigned pk = (unsigned)f2bf(v) | ((unsigned)f2bf(oth) << 16);
                  st32(fi_ring + ((size_t)(tc & 15) * 128 + row + r) * H_ + n, pk);
                }
              }
            }
          }
      }
      __syncthreads();   // drains all waves' ring stores before flag publish
      if (tid == 0) {
        unsigned int* fl = isXG ? (flags + FL_XGF(s) + (tc & 15))
                                : (isFO ? (flags + FL_FOF + (tc & 15)) : (flags + FL_FIF + (tc & 15)));
        st32(fl, (unsigned)(tc + 1));
        st32(myprog, (unsigned)(tc + 1));
      }
    }
  }
}

// ---------------------------------------------------------------------------
__global__ void k_head(const float* __restrict__ hW, const float* __restrict__ hb,
                       unsigned char* ws, float* __restrict__ out) {
  __shared__ float red[256];
  const float* h4 = (const float*)(ws + OFF_H4);
  int tid = threadIdx.x;
  int b = tid >> 4, k0 = tid & 15;
  float sum = 0.f;
  for (int k = k0; k < H_; k += 16) sum += h4[b * H_ + k] * hW[k];
  red[tid] = sum;
  __syncthreads();
  if (tid < B_) {
    float z = hb[0];
    for (int i = 0; i < 16; ++i) z += red[tid * 16 + i];
    out[tid] = 1.0f / (1.0f + __expf(-z));
  }
}

// ---------------------------------------------------------------------------
extern "C" void kernel_launch(void* const* d_in, const int* in_sizes, int n_in,
                              void* d_out, int out_size, void* d_ws, size_t ws_size,
                              hipStream_t stream) {
  const float* x    = (const float*)d_in[0];
  const float* w0ih = (const float*)d_in[1];
  const float* w0hh = (const float*)d_in[2];
  const float* b0   = (const float*)d_in[3];
  const float* foW  = (const float*)d_in[4];
  const float* fob  = (const float*)d_in[5];
  const float* fiW  = (const float*)d_in[6];
  const float* fib  = (const float*)d_in[7];
  const float* w1ih = (const float*)d_in[8];
  const float* w1hh = (const float*)d_in[9];
  const float* b1   = (const float*)d_in[10];
  const float* hW   = (const float*)d_in[11];
  const float* hb   = (const float*)d_in[12];
  unsigned char* ws = (unsigned char*)d_ws;
  (void)in_sizes; (void)n_in; (void)out_size; (void)ws_size;

  hipLaunchKernelGGL(k_prep, dim3(7168), dim3(256), 0, stream, w0ih, w1ih, foW, fiW, ws);
  hipLaunchKernelGGL(k_pipe, dim3(NBLK), dim3(256), 0, stream,
                     x, w0hh, b0, fob, fib, w1hh, b1, ws);
  hipLaunchKernelGGL(k_head, dim3(1), dim3(256), 0, stream, hW, hb, ws, (float*)d_out);
}

// Round 4
// 6062.651 us; speedup vs baseline: 1.8027x; 1.8027x over previous
//
#include <hip/hip_runtime.h>
#include <stdint.h>

// ---------------------------------------------------------------------------
// 4-layer stacked LSTM -> fanout/LeakyReLU/fanin -> LSTM -> head(sigmoid)
// persistent producer/consumer pipeline.
//
// R5 (base = R2, the 7766us kernel; R4's wave-decoupled LLC scheme regressed):
//  * counted s_waitcnt vmcnt(8): ring stores issued FIRST, xg prefetch after,
//    so the store-ack wait does NOT drain the prefetch (R2/R4 both did).
//  * raw s_barrier (+compiler fences) instead of __syncthreads in the step
//    loop -> no barrier re-drains the in-flight prefetch.
//  * per-part step flags (own 64B lines) replace the serialized fetch_add
//    arrival counter.
//  * waves 0..2 each own one foreign part: tight (no s_sleep) poll on that
//    part's flag, then pull its 2KB quarter into the LDS next buffer.
//    max(detect)+gather -> max(detect+gather).
//  * A-fragments stay in LDS (R4's LLC A-reads were the big loss).
//  * All cross-block traffic stays RELAXED AGENT scope (LLC) - the regime
//    R2 proved correct.
// ---------------------------------------------------------------------------

#define B_ 16
#define T_ 2048
#define H_ 256
#define NG 1024
#define F_ 1024
#define CHUNK 8
#define NCH 256            // T_/CHUNK
#define WH 128             // h ring depth (steps)
#define WXG 128            // xg ring depth (steps)
#define WCH 16             // chunk-granular ring depth
#define PREC 4
#define NRECB 20
#define NBLK 56
#define APITCH 264         // LDS row pitch (bf16 elems)
#define WELEM 262144       // 1024*256

typedef __attribute__((ext_vector_type(4))) float f32x4;
typedef __attribute__((ext_vector_type(8))) short bf16x8;
typedef unsigned long long ull;

// ---- workspace layout ----
#define OFF_XG   0ul
#define SZ_XG    (5ul*WXG*NG*B_*4ul)                 // f32 [5][128][1024][16]
#define OFF_H    (OFF_XG + SZ_XG)
#define SZ_H     (5ul*WH*B_*H_*2ul)                  // bf16 [5][128][16][256]
#define OFF_FO   (OFF_H + SZ_H)
#define SZ_FO    ((unsigned long)WCH*128ul*F_*2ul)   // bf16 [16][128][1024]
#define OFF_FI   (OFF_FO + SZ_FO)
#define SZ_FI    ((unsigned long)WCH*128ul*H_*2ul)   // bf16 [16][128][256]
#define OFF_WBF  (OFF_FI + SZ_FI)
#define SZ_WBF   (7ul*WELEM*2ul)
#define OFF_H4   (OFF_WBF + SZ_WBF)
#define OFF_FLAG (OFF_H4 + 16384ul + 256ul)

// flag word indices (64B-line padded where contended)
#define FL_PF(l,p) ((((l)*4)+(p))*16)   // [20] per-part step flags, value t+1
#define FL_XGF(s)  (320 + (s)*16)       // [16] slots per stage, value tc+1
#define FL_FOF     400                  // [16]
#define FL_FIF     416                  // [16]
#define FL_XGP(s)  (432 + (s)*4)        // [5][4] producer progress (chunks)
#define FL_FOP     452                  // [8]
#define FL_FIP     460                  // [8]
#define FL_N       512

#define BAR() do { asm volatile("" ::: "memory"); \
                   __builtin_amdgcn_s_barrier(); \
                   asm volatile("" ::: "memory"); } while (0)

__device__ __forceinline__ unsigned short f2bf(float f) {
  unsigned int u = __float_as_uint(f);
  u = u + 0x7fffu + ((u >> 16) & 1u);
  return (unsigned short)(u >> 16);
}
__device__ __forceinline__ float sigm_f(float x) { return 1.0f / (1.0f + __expf(-x)); }
__device__ __forceinline__ float tanh_f(float x) {
  float e = __expf(-2.0f * fabsf(x));
  float r = (1.0f - e) / (1.0f + e);
  return x >= 0.0f ? r : -r;
}
__device__ __forceinline__ unsigned ld32(const void* p) {
  return __hip_atomic_load((const unsigned*)p, __ATOMIC_RELAXED, __HIP_MEMORY_SCOPE_AGENT);
}
__device__ __forceinline__ void st32(void* p, unsigned v) {
  __hip_atomic_store((unsigned*)p, v, __ATOMIC_RELAXED, __HIP_MEMORY_SCOPE_AGENT);
}
__device__ __forceinline__ ull ld64(const void* p) {
  return __hip_atomic_load((const ull*)p, __ATOMIC_RELAXED, __HIP_MEMORY_SCOPE_AGENT);
}
__device__ __forceinline__ void st64(void* p, ull v) {
  __hip_atomic_store((ull*)p, v, __ATOMIC_RELAXED, __HIP_MEMORY_SCOPE_AGENT);
}
// long-wait spin (chunk granular, off critical path): sleep back-off
__device__ __forceinline__ void spin_ge(unsigned int* p, unsigned int tgt) {
  int n = 0;
  while (ld32(p) < tgt) {
    __builtin_amdgcn_s_sleep(1);
    if (++n > 20000000) break;
  }
}
// short-wait spin (per-step flags): tight poll, no sleep
__device__ __forceinline__ void spin_tight(unsigned int* p, unsigned int tgt) {
  int n = 0;
  while (ld32(p) < tgt) {
    if (++n > 200000) break;
  }
}

// ---------------------------------------------------------------------------
__global__ void k_prep(const float* __restrict__ w0ih, const float* __restrict__ w1ih,
                       const float* __restrict__ foW, const float* __restrict__ fiW,
                       unsigned char* ws) {
  unsigned short* wbf = (unsigned short*)(ws + OFF_WBF);
  unsigned int* flags = (unsigned int*)(ws + OFF_FLAG);
  if (blockIdx.x == 0) {
    for (int i = threadIdx.x; i < FL_N; i += 256) flags[i] = 0u;
  }
  int gid = blockIdx.x * 256 + threadIdx.x;
  if (gid < 7 * WELEM) {
    int which = gid >> 18;
    int idx = gid & (WELEM - 1);
    float v;
    if (which < 4)       v = w0ih[(size_t)which * WELEM + idx];
    else if (which == 4) v = w1ih[idx];
    else if (which == 5) v = foW[idx];
    else                 v = fiW[idx];
    wbf[gid] = f2bf(v);
  }
}

// ---------------------------------------------------------------------------
// issue the 8 xg ring loads (agent/LLC) for step TT into register buffer DST
#define ISSUE_XA(TT, DST) do { \
    const ull* xg8_ = (const ull*)(xg_ring + ((size_t)l * WXG + (size_t)((TT) & 127)) * (NG * B_)); \
    _Pragma("unroll") \
    for (int g_ = 0; g_ < 4; ++g_) { \
      size_t n8_ = (size_t)(g_ * 256 + unit) * 8 + quad * 2; \
      DST[g_][0] = ld64(xg8_ + n8_); \
      DST[g_][1] = ld64(xg8_ + n8_ + 1); \
    } \
  } while (0)

// One recurrent step. CB = t&1 (compile-time at each expansion site).
// XC = xg regs for this step (already in flight), XN = buffer to prefetch t+1.
#define REC_STEP(T, CB, XC, XN) do { \
    const int t_ = (T); \
    if ((t_ & 7) == 0) { \
      int tc_ = t_ >> 3; \
      if (wave == 0) { \
        unsigned int* wp_ = (unsigned int*)0; unsigned wt_ = 0u; \
        if (lane == 0) { wp_ = xgf + (tc_ & 15); wt_ = (unsigned)(tc_ + 1); }  /* xg chunk ready */ \
        else if (l < 4 && tc_ >= WCH) {                                        /* h-ring overwrite guard */ \
          unsigned g_ = (unsigned)(tc_ - WCH + 1); \
          if (l < 3) { if (lane >= 1 && lane <= 4) { wp_ = flags + FL_XGP(l + 1) + (lane - 1); wt_ = g_; } } \
          else       { if (lane >= 1 && lane <= 8) { wp_ = flags + FL_FOP + (lane - 1); wt_ = g_; } } \
        } \
        if (wp_) spin_ge(wp_, wt_); \
      } \
      BAR(); \
      ISSUE_XA(t_, XC); \
    } \
    /* gates = h . Whh^T  (A from LDS cur buffer) */ \
    f32x4 ac_[4]; \
    _Pragma("unroll") for (int g_ = 0; g_ < 4; ++g_) ac_[g_] = (f32x4){0.f, 0.f, 0.f, 0.f}; \
    _Pragma("unroll") \
    for (int kk_ = 0; kk_ < 8; ++kk_) { \
      bf16x8 af_ = *(const bf16x8*)(&smem[(CB) * 16 * APITCH + c16 * APITCH + kk_ * 32 + quad * 8]); \
      _Pragma("unroll") \
      for (int g_ = 0; g_ < 4; ++g_) \
        ac_[g_] = __builtin_amdgcn_mfma_f32_16x16x32_bf16(af_, bfr[g_][kk_], ac_[g_], 0, 0, 0); \
    } \
    /* elementwise cell; lane owns (b=quad*4+r, unit) */ \
    float hv_[4]; \
    _Pragma("unroll") \
    for (int r_ = 0; r_ < 4; ++r_) { \
      union { ull u; float f[2]; } u0_, u1_, u2_, u3_; \
      u0_.u = XC[0][r_ >> 1]; u1_.u = XC[1][r_ >> 1]; \
      u2_.u = XC[2][r_ >> 1]; u3_.u = XC[3][r_ >> 1]; \
      float iv_ = sigm_f(ac_[0][r_] + u0_.f[r_ & 1]); \
      float fv_ = sigm_f(ac_[1][r_] + u1_.f[r_ & 1]); \
      float gv_ = tanh_f(ac_[2][r_] + u2_.f[r_ & 1]); \
      float ov_ = sigm_f(ac_[3][r_] + u3_.f[r_ & 1]); \
      cst[r_] = fv_ * cst[r_] + iv_ * gv_; \
      hv_[r_] = ov_ * tanh_f(cst[r_]); \
      if (l == 4 && t_ == T_ - 1) h4_last[(quad * 4 + r_) * H_ + unit] = hv_[r_]; \
    } \
    /* pack bf16 pairs via shfl */ \
    unsigned pk_[4]; \
    _Pragma("unroll") \
    for (int r_ = 0; r_ < 4; ++r_) { \
      float oth_ = __shfl_xor(hv_[r_], 1, 64); \
      pk_[r_] = (unsigned)f2bf(hv_[r_]) | ((unsigned)f2bf(oth_) << 16); \
    } \
    /* ring stores FIRST (oldest vmem ops) ... */ \
    { unsigned short* hrw_ = h_ring + ((size_t)l * WH + (size_t)(t_ & 127)) * (B_ * H_); \
      if ((lane & 1) == 0) { \
        _Pragma("unroll") \
        for (int r_ = 0; r_ < 4; ++r_) \
          st32(hrw_ + (size_t)(quad * 4 + r_) * H_ + unit, pk_[r_]); \
      } } \
    asm volatile("" ::: "memory");          /* pin order: stores before prefetch */ \
    if ((t_ & 7) != 7) ISSUE_XA(t_ + 1, XN);   /* prefetch next step's xg */ \
    /* LDS own quarter -> next buffer (lgkm counter, independent) */ \
    if ((lane & 1) == 0) { \
      _Pragma("unroll") \
      for (int r_ = 0; r_ < 4; ++r_) \
        *(unsigned*)&smem[(((CB) ^ 1) * 16 + (quad * 4 + r_)) * APITCH + unit] = pk_[r_]; \
    } \
    /* wait ring stores acked at LLC, prefetch stays in flight */ \
    if ((t_ & 7) != 7) { asm volatile("s_waitcnt vmcnt(8)" ::: "memory"); } \
    else               { asm volatile("s_waitcnt vmcnt(0)" ::: "memory"); } \
    BAR();                                   /* A: all 4 waves' stores acked */ \
    if (tid == 0) st32(mypf, (unsigned)(t_ + 1)); \
    /* waves 0..2: own one foreign part - poll tight, pull 2KB into LDS nxt */ \
    if (wave < 3) { \
      int fp_ = (p + 1 + wave) & 3; \
      spin_tight(flags + FL_PF(l, fp_), (unsigned)(t_ + 1)); \
      int b2_ = lane >> 2, q4_ = lane & 3; \
      const ull* src8_ = (const ull*)(h_ring + ((size_t)l * WH + (size_t)(t_ & 127)) * (B_ * H_) + \
                                      (size_t)b2_ * H_ + fp_ * 64 + q4_ * 16); \
      ull v0_ = ld64(src8_ + 0), v1_ = ld64(src8_ + 1); \
      ull v2_ = ld64(src8_ + 2), v3_ = ld64(src8_ + 3); \
      ull* dst8_ = (ull*)&smem[(((CB) ^ 1) * 16 + b2_) * APITCH + fp_ * 64 + q4_ * 16]; \
      dst8_[0] = v0_; dst8_[1] = v1_; dst8_[2] = v2_; dst8_[3] = v3_; \
    } \
    asm volatile("s_waitcnt lgkmcnt(0)" ::: "memory"); \
    BAR();                                   /* B: nxt buffer complete */ \
  } while (0)

// ---------------------------------------------------------------------------
__global__ __launch_bounds__(256, 1) void k_pipe(
    const float* __restrict__ x,
    const float* __restrict__ w0hh, const float* __restrict__ b0,
    const float* __restrict__ fo_b, const float* __restrict__ fi_b,
    const float* __restrict__ w1hh, const float* __restrict__ b1,
    unsigned char* ws)
{
  __shared__ unsigned short smem[64 * APITCH];   // 33792 B (REC uses first 2*16 rows)

  float*          xg_ring = (float*)(ws + OFF_XG);
  unsigned short* h_ring  = (unsigned short*)(ws + OFF_H);
  unsigned short* fo_ring = (unsigned short*)(ws + OFF_FO);
  unsigned short* fi_ring = (unsigned short*)(ws + OFF_FI);
  unsigned short* wbf     = (unsigned short*)(ws + OFF_WBF);
  float*          h4_last = (float*)(ws + OFF_H4);
  unsigned int*   flags   = (unsigned int*)(ws + OFF_FLAG);

  const int tid = threadIdx.x;
  const int lane = tid & 63;
  const int wave = tid >> 6;
  const int quad = lane >> 4;
  const int c16 = lane & 15;
  const int bid = blockIdx.x;

  if (bid < NRECB) {
    // ================= recurrent role: layer l, part p =================
    const int l = bid / PREC, p = bid % PREC;
    const int unit = (p * 4 + wave) * 16 + c16;   // global unit 0..255
    const float* Whh = (l < 4) ? (w0hh + (size_t)l * NG * H_) : w1hh;

    bf16x8 bfr[4][8];   // B-frags: Whh[n][k], n = gate*256+unit
#pragma unroll
    for (int g = 0; g < 4; ++g) {
      const float* rp = Whh + (size_t)(g * 256 + unit) * H_ + quad * 8;
#pragma unroll
      for (int kk = 0; kk < 8; ++kk) {
        const float* q = rp + kk * 32;
        bf16x8 pk;
#pragma unroll
        for (int jj = 0; jj < 8; ++jj) pk[jj] = (short)f2bf(q[jj]);
        bfr[g][kk] = pk;
      }
    }
    for (int i = tid; i < 2 * 16 * APITCH; i += 256) smem[i] = 0;  // h(-1)=0
    float cst[4] = {0.f, 0.f, 0.f, 0.f};
    __syncthreads();

    unsigned int* xgf  = flags + FL_XGF(l);
    unsigned int* mypf = flags + FL_PF(l, p);

    ull xaA[4][2], xaB[4][2];
    for (int t2 = 0; t2 < T_; t2 += 2) {
      REC_STEP(t2,     0, xaA, xaB);
      REC_STEP(t2 + 1, 1, xaB, xaA);
    }
  } else {
    // ================= stream roles =================
    int sb = bid - NRECB, s, j, GSS;
    if (sb < 20)      { s = sb >> 2; j = sb & 3;  GSS = 4; }
    else if (sb < 28) { s = 5;       j = sb - 20; GSS = 8; }
    else              { s = 6;       j = sb - 28; GSS = 8; }
    const bool isXG = (s < 5), isFO = (s == 5), isFI = (s == 6);
    const unsigned short* Bw = wbf + (size_t)(isXG ? s : (isFO ? 5 : 6)) * WELEM;
    const float* bias = isXG ? ((s < 4) ? (b0 + s * NG) : b1) : (isFO ? fo_b : fi_b);
    unsigned int* myprog =
        flags + (isXG ? (FL_XGP(s) + j) : (isFO ? (FL_FOP + j) : (FL_FIP + j)));

    for (int tc = j; tc < NCH; tc += GSS) {
      // output-ring overwrite guard (lane-parallel)
      if (tc >= WCH) {
        unsigned int tgt = (unsigned)(tc - WCH + 1);
        if (isXG)      { if (tid < 4) spin_ge(flags + FL_PF(s, tid), 8u * tgt); }
        else if (isFO) { if (tid < 8) spin_ge(flags + FL_FIP + tid, tgt); }
        else           { if (tid < 4) spin_ge(flags + FL_XGP(4) + tid, tgt); }
      }
      // input readiness
      if (isXG) {
        if (s >= 1 && s <= 3) { if (tid < 4) spin_ge(flags + FL_PF(s - 1, tid), 8u * (unsigned)(tc + 1)); }
        else if (s == 4)      { if (tid == 0) spin_ge(flags + FL_FIF + (tc & 15), (unsigned)(tc + 1)); }
      } else if (isFO) {
        if (tid < 4) spin_ge(flags + FL_PF(3, tid), 8u * (unsigned)(tc + 1));
      } else {
        if (tid == 0) spin_ge(flags + FL_FOF + (tc & 15), (unsigned)(tc + 1));
      }
      __syncthreads();

      if (!isFI) {
        // [128,256] x [256,1024]
#pragma unroll
        for (int m_blk = 0; m_blk < 2; ++m_blk) {
          __syncthreads();
          { // stage 64 A rows into LDS (bf16)
            int rloc = tid >> 2;
            int k0 = (tid & 3) * 64;
            int row = m_blk * 64 + rloc;
            int tl = row >> 4, b = row & 15;
            int t = tc * CHUNK + tl;
            unsigned short* dst = &smem[rloc * APITCH + k0];
            if (s == 0) {
              const float* src = x + ((size_t)b * T_ + t) * H_ + k0;
#pragma unroll
              for (int i = 0; i < 16; ++i) {
                f32x4 v = *(const f32x4*)(src + i * 4);
                *(unsigned*)(dst + i * 4)     = (unsigned)f2bf(v[0]) | ((unsigned)f2bf(v[1]) << 16);
                *(unsigned*)(dst + i * 4 + 2) = (unsigned)f2bf(v[2]) | ((unsigned)f2bf(v[3]) << 16);
              }
            } else {
              const unsigned short* src;
              if (isXG && s <= 3)
                src = h_ring + ((size_t)(s - 1) * WH + (size_t)(t & 127)) * (B_ * H_) + b * H_ + k0;
              else if (isXG)  // s==4: fan-in output
                src = fi_ring + ((size_t)(tc & 15) * 128 + row) * H_ + k0;
              else            // FO: h3
                src = h_ring + ((size_t)3 * WH + (size_t)(t & 127)) * (B_ * H_) + b * H_ + k0;
#pragma unroll
              for (int i = 0; i < 16; ++i)
                *(ull*)(dst + i * 4) = ld64((const ull*)src + i);
            }
          }
          __syncthreads();
          bf16x8 afr[4][8];
#pragma unroll
          for (int mt = 0; mt < 4; ++mt)
#pragma unroll
            for (int kk = 0; kk < 8; ++kk)
              afr[mt][kk] = *(const bf16x8*)(&smem[(mt * 16 + c16) * APITCH + kk * 32 + quad * 8]);
          for (int nn = 0; nn < 16; ++nn) {
            int n = (wave * 16 + nn) * 16 + c16;
            const unsigned short* bp = Bw + (size_t)n * 256 + quad * 8;
            bf16x8 bfr2[8];
#pragma unroll
            for (int kk = 0; kk < 8; ++kk) bfr2[kk] = *(const bf16x8*)(bp + kk * 32);
            f32x4 ac[4];
#pragma unroll
            for (int mt = 0; mt < 4; ++mt) ac[mt] = (f32x4){0.f, 0.f, 0.f, 0.f};
#pragma unroll
            for (int kk = 0; kk < 8; ++kk)
#pragma unroll
              for (int mt = 0; mt < 4; ++mt)
                ac[mt] = __builtin_amdgcn_mfma_f32_16x16x32_bf16(afr[mt][kk], bfr2[kk], ac[mt], 0, 0, 0);
            float bn = bias[n];
            if (isXG) {
              ull* xg8 = (ull*)(xg_ring + (size_t)s * WXG * (NG * B_));
#pragma unroll
              for (int mt = 0; mt < 4; ++mt) {
                int t = tc * CHUNK + m_blk * 4 + mt;
                size_t bi = ((size_t)(t & 127) * (NG * B_) + (size_t)n * B_ + quad * 4) >> 1;
                union { ull u; float f[2]; } u0, u1;
                u0.f[0] = ac[mt][0] + bn; u0.f[1] = ac[mt][1] + bn;
                u1.f[0] = ac[mt][2] + bn; u1.f[1] = ac[mt][3] + bn;
                st64(xg8 + bi, u0.u);
                st64(xg8 + bi + 1, u1.u);
              }
            } else {  // FO: bias + LeakyReLU -> bf16 ring
#pragma unroll
              for (int mt = 0; mt < 4; ++mt) {
                int row = m_blk * 64 + mt * 16 + quad * 4;
#pragma unroll
                for (int r = 0; r < 4; ++r) {
                  float v = ac[mt][r] + bn;
                  v = v >= 0.f ? v : 0.2f * v;
                  float oth = __shfl_xor(v, 1, 64);
                  if ((lane & 1) == 0) {
                    unsigned pk = (unsigned)f2bf(v) | ((unsigned)f2bf(oth) << 16);
                    st32(fo_ring + ((size_t)(tc & 15) * 128 + row + r) * F_ + n, pk);
                  }
                }
              }
            }
          }
        }
      } else {
        // FI: [128,1024] x [1024,256]
        f32x4 acc[2][4][4];
#pragma unroll
        for (int a1 = 0; a1 < 2; ++a1)
#pragma unroll
          for (int a2 = 0; a2 < 4; ++a2)
#pragma unroll
            for (int a3 = 0; a3 < 4; ++a3) acc[a1][a2][a3] = (f32x4){0.f, 0.f, 0.f, 0.f};
#pragma unroll
        for (int ks = 0; ks < 4; ++ks) {
#pragma unroll
          for (int m_blk = 0; m_blk < 2; ++m_blk) {
            __syncthreads();
            {
              int rloc = tid >> 2;
              int k0 = (tid & 3) * 64;
              int row = m_blk * 64 + rloc;
              const unsigned short* src =
                  fo_ring + ((size_t)(tc & 15) * 128 + row) * F_ + ks * 256 + k0;
              unsigned short* dst = &smem[rloc * APITCH + k0];
#pragma unroll
              for (int i = 0; i < 16; ++i)
                *(ull*)(dst + i * 4) = ld64((const ull*)src + i);
            }
            __syncthreads();
            bf16x8 afr[4][8];
#pragma unroll
            for (int mt = 0; mt < 4; ++mt)
#pragma unroll
              for (int kk = 0; kk < 8; ++kk)
                afr[mt][kk] = *(const bf16x8*)(&smem[(mt * 16 + c16) * APITCH + kk * 32 + quad * 8]);
#pragma unroll
            for (int nn = 0; nn < 4; ++nn) {
              int n = (wave * 4 + nn) * 16 + c16;
              const unsigned short* bp = Bw + (size_t)n * 1024 + ks * 256 + quad * 8;
              bf16x8 bfr2[8];
#pragma unroll
              for (int kk = 0; kk < 8; ++kk) bfr2[kk] = *(const bf16x8*)(bp + kk * 32);
#pragma unroll
              for (int kk = 0; kk < 8; ++kk)
#pragma unroll
                for (int mt = 0; mt < 4; ++mt)
                  acc[m_blk][nn][mt] =
                      __builtin_amdgcn_mfma_f32_16x16x32_bf16(afr[mt][kk], bfr2[kk], acc[m_blk][nn][mt], 0, 0, 0);
            }
          }
        }
#pragma unroll
        for (int m_blk = 0; m_blk < 2; ++m_blk)
#pragma unroll
          for (int nn = 0; nn < 4; ++nn) {
            int n = (wave * 4 + nn) * 16 + c16;
            float bn = bias[n];
#pragma unroll
            for (int mt = 0; mt < 4; ++mt) {
              int row = m_blk * 64 + mt * 16 + quad * 4;
#pragma unroll
              for (int r = 0; r < 4; ++r) {
                float v = acc[m_blk][nn][mt][r] + bn;
                float oth = __shfl_xor(v, 1, 64);
                if ((lane & 1) == 0) {
                  unsigned pk = (unsigned)f2bf(v) | ((unsigned)f2bf(oth) << 16);
                  st32(fi_ring + ((size_t)(tc & 15) * 128 + row + r) * H_ + n, pk);
                }
              }
            }
          }
      }
      __syncthreads();   // drains all waves' ring stores before flag publish
      if (tid == 0) {
        unsigned int* fl = isXG ? (flags + FL_XGF(s) + (tc & 15))
                                : (isFO ? (flags + FL_FOF + (tc & 15)) : (flags + FL_FIF + (tc & 15)));
        st32(fl, (unsigned)(tc + 1));
        st32(myprog, (unsigned)(tc + 1));
      }
    }
  }
}

// ---------------------------------------------------------------------------
__global__ void k_head(const float* __restrict__ hW, const float* __restrict__ hb,
                       unsigned char* ws, float* __restrict__ out) {
  __shared__ float red[256];
  const float* h4 = (const float*)(ws + OFF_H4);
  int tid = threadIdx.x;
  int b = tid >> 4, k0 = tid & 15;
  float sum = 0.f;
  for (int k = k0; k < H_; k += 16) sum += h4[b * H_ + k] * hW[k];
  red[tid] = sum;
  __syncthreads();
  if (tid < B_) {
    float z = hb[0];
    for (int i = 0; i < 16; ++i) z += red[tid * 16 + i];
    out[tid] = 1.0f / (1.0f + __expf(-z));
  }
}

// ---------------------------------------------------------------------------
extern "C" void kernel_launch(void* const* d_in, const int* in_sizes, int n_in,
                              void* d_out, int out_size, void* d_ws, size_t ws_size,
                              hipStream_t stream) {
  const float* x    = (const float*)d_in[0];
  const float* w0ih = (const float*)d_in[1];
  const float* w0hh = (const float*)d_in[2];
  const float* b0   = (const float*)d_in[3];
  const float* foW  = (const float*)d_in[4];
  const float* fob  = (const float*)d_in[5];
  const float* fiW  = (const float*)d_in[6];
  const float* fib  = (const float*)d_in[7];
  const float* w1ih = (const float*)d_in[8];
  const float* w1hh = (const float*)d_in[9];
  const float* b1   = (const float*)d_in[10];
  const float* hW   = (const float*)d_in[11];
  const float* hb   = (const float*)d_in[12];
  unsigned char* ws = (unsigned char*)d_ws;
  (void)in_sizes; (void)n_in; (void)out_size; (void)ws_size;

  hipLaunchKernelGGL(k_prep, dim3(7168), dim3(256), 0, stream, w0ih, w1ih, foW, fiW, ws);
  hipLaunchKernelGGL(k_pipe, dim3(NBLK), dim3(256), 0, stream,
                     x, w0hh, b0, fob, fib, w1hh, b1, ws);
  hipLaunchKernelGGL(k_head, dim3(1), dim3(256), 0, stream, hW, hb, ws, (float*)d_out);
}